// Round 8
// baseline (521.984 us; speedup 1.0000x reference)
//
#include <hip/hip_runtime.h>
#include <hip/hip_cooperative_groups.h>

namespace cg = cooperative_groups;

#define NN 32768      // N = N_FEAT * LONG * LAT
#define BB 128        // batch
#define OUT_F 256     // output features
#define MPAD 8192     // padded active-extent cap (actual M = 4103)
#define KS 64         // gemm k-slice width
#define NSL (MPAD / KS)
#define NBLK 512
#define NTHR 256

struct SharedU {
  union {
    float tile[64][65];                              // phase 0 transpose
    struct { float h1s[KS][BB]; float Wt[KS][64]; } g;  // phase 5 gemm (48 KB)
    int wsum[8];                                     // phase 2 scan
  };
};

// One cooperative kernel, 7 phases separated by grid.sync().
__global__ void __launch_bounds__(NTHR, 2) k_mega(
    const int* __restrict__ rows, const int* __restrict__ cols,
    const float* __restrict__ vals, int nnz,
    const float* __restrict__ x, const float* __restrict__ W,
    const float* __restrict__ bias,
    int* Mp, int* offs, int2* ent, float* xT, float* h1,
    float* part, float* out) {
  cg::grid_group grid = cg::this_grid();
  __shared__ SharedU sm;
  const int bid = blockIdx.x;
  const int t = threadIdx.x;
  const int lane = t & 63;

  // ---- phase 0: blocks 0..255 transpose xT[c][b] = x[b][c] (64x64 LDS
  //      tiles over full MPAD); blocks 256..511 zero offs + Mp. ----
  if (bid < 256) {
    int c0 = (bid & 127) * 64;
    int b0 = (bid >> 7) * 64;
    int tx = t & 63, ty = t >> 6;
    #pragma unroll
    for (int i = 0; i < 64; i += 4)
      sm.tile[ty + i][tx] = x[(long)(b0 + ty + i) * NN + (c0 + tx)];
    __syncthreads();
    #pragma unroll
    for (int i = 0; i < 64; i += 4)
      xT[(long)(c0 + i + ty) * BB + b0 + tx] = sm.tile[tx][i + ty];
  } else {
    int idx = (bid - 256) * NTHR + t;
    if (idx < MPAD) offs[idx] = 0;
    if (idx == 0) *Mp = 0;
  }
  grid.sync();

  // ---- phase 1: run-aggregated row histogram + extent max ----
  {
    int gid = bid * NTHR + t;
    const int stride = NBLK * NTHR;
    int m = 0;
    for (int e = gid;; e += stride) {
      bool valid = e < nnz;
      if (!__any(valid)) break;
      int r = valid ? rows[e] : -1;
      int c = valid ? cols[e] : -1;
      m = max(m, max(r, c));
      int rprev = __shfl_up(r, 1);
      bool head = (lane == 0) || (r != rprev);
      unsigned long long mask = __ballot(head);
      if (head && r >= 0) {
        int count;
        if (lane == 63) count = 1;
        else {
          unsigned long long rest = mask >> (lane + 1);
          count = rest ? __ffsll(rest) : (64 - lane);
        }
        atomicAdd(&offs[r], count);
      }
    }
    #pragma unroll
    for (int off = 32; off > 0; off >>= 1) m = max(m, __shfl_down(m, off));
    if (lane == 0) atomicMax(Mp, m + 1);
  }
  grid.sync();

  // ---- phase 2: exclusive scan of offs[0:MPAD] (block 0; 256 thr x 32) ----
  if (bid == 0) {
    int base = t * 32;
    int v[32];
    int s = 0;
    #pragma unroll
    for (int j = 0; j < 32; ++j) { v[j] = offs[base + j]; s += v[j]; }
    int tot = s;
    #pragma unroll
    for (int d = 1; d < 64; d <<= 1) {
      int n = __shfl_up(s, d);
      if (lane >= d) s += n;
    }
    int wid = t >> 6;
    if (lane == 63) sm.wsum[wid] = s;
    __syncthreads();
    if (t < 4) {
      int w = sm.wsum[t];
      #pragma unroll
      for (int d = 1; d < 4; d <<= 1) {
        int n = __shfl_up(w, d);
        if (t >= d) w += n;
      }
      sm.wsum[t] = w;
    }
    __syncthreads();
    int run = (wid ? sm.wsum[wid - 1] : 0) + (s - tot);  // exclusive start
    #pragma unroll
    for (int j = 0; j < 32; ++j) { offs[base + j] = run; run += v[j]; }
  }
  grid.sync();

  // ---- phase 3: bucket COO -> CSR (run-aggregated position atomics) ----
  {
    int gid = bid * NTHR + t;
    const int stride = NBLK * NTHR;
    for (int e = gid;; e += stride) {
      bool valid = e < nnz;
      if (!__any(valid)) break;
      int r = valid ? rows[e] : -1;
      int rprev = __shfl_up(r, 1);
      bool head = (lane == 0) || (r != rprev);
      unsigned long long mask = __ballot(head);
      unsigned long long below =
          (lane == 63) ? mask : (mask & ((1ULL << (lane + 1)) - 1));
      int head_idx = 63 - __clzll(below);
      int rank = lane - head_idx;
      int base = 0;
      if (head && r >= 0) {
        int count;
        if (lane == 63) count = 1;
        else {
          unsigned long long rest = mask >> (lane + 1);
          count = rest ? __ffsll(rest) : (64 - lane);
        }
        base = atomicAdd(&offs[r], count);
      }
      base = __shfl(base, head_idx);
      if (valid) ent[base + rank] = make_int2(cols[e], __float_as_int(vals[e]));
    }
  }
  grid.sync();

  // ---- phase 4: CSR gather (wave per row; coalesced 64-entry blocks with
  //      prefetch; shfl broadcast; 4 independent accumulator pairs) ----
  {
    int M = *Mp;
    int wave = bid * 4 + (t >> 6);
    int nw = NBLK * 4;
    const float2* xT2 = (const float2*)xT;
    float2* h12 = (float2*)h1;
    for (int r = wave; r < M; r += nw) {
      int start = r ? offs[r - 1] : 0;
      int end = offs[r];
      float a0x = 0, a0y = 0, a1x = 0, a1y = 0;
      float a2x = 0, a2y = 0, a3x = 0, a3y = 0;
      int jb = start;
      int2 ecur = make_int2(0, 0), enext = make_int2(0, 0);
      if (jb < end) {
        int n0 = end - jb; if (n0 > 64) n0 = 64;
        ecur = ent[jb + min(lane, n0 - 1)];
      }
      while (jb < end) {
        int n = end - jb; if (n > 64) n = 64;
        int jn = jb + 64;
        if (jn < end) {
          int n2 = end - jn; if (n2 > 64) n2 = 64;
          enext = ent[jn + min(lane, n2 - 1)];
        }
        int s = 0;
        for (; s + 3 < n; s += 4) {
          int c0 = __shfl(ecur.x, s);
          int c1 = __shfl(ecur.x, s + 1);
          int c2 = __shfl(ecur.x, s + 2);
          int c3 = __shfl(ecur.x, s + 3);
          float v0 = __int_as_float(__shfl(ecur.y, s));
          float v1 = __int_as_float(__shfl(ecur.y, s + 1));
          float v2 = __int_as_float(__shfl(ecur.y, s + 2));
          float v3 = __int_as_float(__shfl(ecur.y, s + 3));
          float2 p0 = xT2[c0 * 64 + lane];
          float2 p1 = xT2[c1 * 64 + lane];
          float2 p2 = xT2[c2 * 64 + lane];
          float2 p3 = xT2[c3 * 64 + lane];
          a0x += v0 * p0.x; a0y += v0 * p0.y;
          a1x += v1 * p1.x; a1y += v1 * p1.y;
          a2x += v2 * p2.x; a2y += v2 * p2.y;
          a3x += v3 * p3.x; a3y += v3 * p3.y;
        }
        for (; s < n; ++s) {
          int c0 = __shfl(ecur.x, s);
          float v0 = __int_as_float(__shfl(ecur.y, s));
          float2 p0 = xT2[c0 * 64 + lane];
          a0x += v0 * p0.x; a0y += v0 * p0.y;
        }
        ecur = enext;
        jb = jn;
      }
      h12[r * 64 + lane] = make_float2(a0x + a1x + a2x + a3x,
                                       a0y + a1y + a2y + a3y);
    }
  }
  grid.sync();

  // ---- phase 5: split-K GEMM partials. block -> (sl = bid>>2, oq = bid&3).
  //      512 tasks = 512 blocks exactly; inactive slices fall through. ----
  {
    int M = *Mp;
    int k0 = (bid >> 2) * KS;
    int o0 = (bid & 3) * 64;
    if (k0 < M) {
      const float4* h1g = (const float4*)h1;
      float4* h1s4 = (float4*)&sm.g.h1s[0][0];
      #pragma unroll
      for (int j = 0; j < 8; ++j) {
        int idx = t + j * 256;
        int kk = idx >> 5;
        int gk = k0 + kk;
        float4 vv = make_float4(0.f, 0.f, 0.f, 0.f);
        if (gk < M) vv = h1g[gk * 32 + (idx & 31)];
        h1s4[idx] = vv;
      }
      #pragma unroll
      for (int j = 0; j < 4; ++j) {
        int idx = t + j * 256;
        int ol = idx & 63;
        int kc = idx >> 6;
        float4 wv = *(const float4*)&W[(size_t)(o0 + ol) * NN + k0 + kc * 4];
        sm.g.Wt[kc * 4 + 0][ol] = wv.x;
        sm.g.Wt[kc * 4 + 1][ol] = wv.y;
        sm.g.Wt[kc * 4 + 2][ol] = wv.z;
        sm.g.Wt[kc * 4 + 3][ol] = wv.w;
      }
      __syncthreads();

      int tb = (t & 15) * 8;
      int to = (t >> 4) * 4;
      float acc[8][4];
      #pragma unroll
      for (int bi = 0; bi < 8; ++bi)
        #pragma unroll
        for (int oj = 0; oj < 4; ++oj) acc[bi][oj] = 0.0f;

      for (int kk = 0; kk < KS; ++kk) {
        float4 a0 = *(const float4*)&sm.g.h1s[kk][tb];
        float4 a1 = *(const float4*)&sm.g.h1s[kk][tb + 4];
        float4 w = *(const float4*)&sm.g.Wt[kk][to];
        float a[8] = {a0.x, a0.y, a0.z, a0.w, a1.x, a1.y, a1.z, a1.w};
        #pragma unroll
        for (int bi = 0; bi < 8; ++bi) {
          acc[bi][0] += a[bi] * w.x;
          acc[bi][1] += a[bi] * w.y;
          acc[bi][2] += a[bi] * w.z;
          acc[bi][3] += a[bi] * w.w;
        }
      }

      float* pb = part + (size_t)(bid >> 2) * (BB * OUT_F);
      #pragma unroll
      for (int bi = 0; bi < 8; ++bi) {
        float4 v = make_float4(acc[bi][0], acc[bi][1], acc[bi][2], acc[bi][3]);
        *(float4*)&pb[(tb + bi) * OUT_F + o0 + to] = v;
      }
    }
  }
  grid.sync();

  // ---- phase 6: reduce partials + bias -> out ----
  {
    int M = *Mp;
    int ns = (M + KS - 1) / KS;
    int gid = bid * NTHR + t;
    if (gid < BB * OUT_F / 4) {
      float4 s = ((const float4*)bias)[gid & 63];
      const float4* p4 = (const float4*)part;
      for (int sl = 0; sl < ns; ++sl) {
        float4 v = p4[(size_t)sl * (BB * OUT_F / 4) + gid];
        s.x += v.x; s.y += v.y; s.z += v.z; s.w += v.w;
      }
      ((float4*)out)[gid] = s;
    }
  }
}

// ---------------------------------------------------------------------------
extern "C" void kernel_launch(void* const* d_in, const int* in_sizes, int n_in,
                              void* d_out, int out_size, void* d_ws,
                              size_t ws_size, hipStream_t stream) {
  const int*   rows = (const int*)d_in[1];
  const int*   cols = (const int*)d_in[2];
  const float* vals = (const float*)d_in[3];
  const float* x    = (const float*)d_in[0];
  const float* W    = (const float*)d_in[4];
  const float* bias = (const float*)d_in[5];
  float* out = (float*)d_out;
  int nnz = in_sizes[1];

  char* ws = (char*)d_ws;
  int*  Mp   = (int*)ws;                                   // 4 B (256 B slot)
  int*  offs = (int*)(ws + 256);                           // MPAD ints
  size_t off_ent = 256 + (size_t)MPAD * 4;
  int2* ent  = (int2*)(ws + off_ent);                      // nnz int2
  size_t entB = ((size_t)nnz * 8 + 255) & ~(size_t)255;
  float* xT  = (float*)(ws + off_ent + entB);              // MPAD*BB floats
  float* h1  = xT + (size_t)MPAD * BB;                     // MPAD*BB floats
  float* part = h1 + (size_t)MPAD * BB;                    // NSL*BB*OUT_F

  void* args[] = {(void*)&rows, (void*)&cols, (void*)&vals, (void*)&nnz,
                  (void*)&x, (void*)&W, (void*)&bias,
                  (void*)&Mp, (void*)&offs, (void*)&ent, (void*)&xT,
                  (void*)&h1, (void*)&part, (void*)&out};
  hipLaunchCooperativeKernel((const void*)k_mega, dim3(NBLK), dim3(NTHR),
                             args, 0, stream);
}